// Round 6
// baseline (246.402 us; speedup 1.0000x reference)
//
#include <hip/hip_runtime.h>
#include <stdint.h>
#include <stddef.h>

typedef __bf16 bf16;
typedef bf16 bf16x4 __attribute__((ext_vector_type(4)));
typedef bf16 bf16x8 __attribute__((ext_vector_type(8)));
typedef float f32x4 __attribute__((ext_vector_type(4)));
typedef float f32x16 __attribute__((ext_vector_type(16)));

#define T_DIM 365
#define SX    376     // x tile stride (bf16): 752B
#define SH    264     // H1-half / H2 stride: 528B
#define SCB   184     // combined stride: 368B
#define SC1   72
#define SC2   33

// ws element offsets (bf16) — fragment-major packed layouts.
// L1: [p(2)][wv(4)][nt(2)][ks(23)][lane(64)][8]  n=256p+64wv+32nt+(l&31), k=16ks+(l>>5)*8+j
#define WT1_OFF  0
// L2: [kh(2)][wv(4)][nt(2)][ks(16)][lane][8]     n=64wv+32nt+(l&31),      k=256kh+16ks+(l>>5)*8+j
#define WT2_OFF  188416
// L3: [wv(4)][ks(16)][lane][8]                   n=32wv+(l&31),           k=16ks+(l>>5)*8+j
#define WT3_OFF  319488
// c1: [g(2)][nt(2)][ks(5)][lane][8]              n=16*(2g+nt)+(l&15),     k=32ks+(l>>4)*8+j
#define WTC1_OFF 352256
// c2: [nt(2)][ks(2)][lane][8]                    n=16nt+(l&15),           k=32ks+(l>>4)*8+j
#define WTC2_OFF 362496
#define WTOTAL   364544

__global__ void prep_weights(const float* __restrict__ W1, const float* __restrict__ W2,
                             const float* __restrict__ W3, const float* __restrict__ Wc1,
                             const float* __restrict__ Wc2, bf16* __restrict__ ws) {
    int idx = blockIdx.x * 256 + threadIdx.x;
    if (idx >= WTOTAL) return;
    if (idx < WT2_OFF) {
        int t = idx;
        int j = t & 7, lane = (t >> 3) & 63, f = t >> 9;
        int ks = f % 23; f /= 23;           // f in [0,16)
        int nt = f & 1; f >>= 1;            // [0,8)
        int wv = f & 3, p = f >> 2;
        int n = 256 * p + 64 * wv + 32 * nt + (lane & 31);
        int k = 16 * ks + (lane >> 5) * 8 + j;
        ws[idx] = (k < T_DIM) ? (bf16)W1[k * 512 + n] : (bf16)0.0f;
    } else if (idx < WT3_OFF) {
        int t = idx - WT2_OFF;
        int j = t & 7, lane = (t >> 3) & 63, f = t >> 9;
        int ks = f & 15; f >>= 4;
        int nt = f & 1; f >>= 1;
        int wv = f & 3, kh = f >> 2;
        int n = 64 * wv + 32 * nt + (lane & 31);
        int k = 256 * kh + 16 * ks + (lane >> 5) * 8 + j;
        ws[idx] = (bf16)W2[k * 256 + n];
    } else if (idx < WTC1_OFF) {
        int t = idx - WT3_OFF;
        int j = t & 7, lane = (t >> 3) & 63, f = t >> 9;
        int ks = f & 15, wv = f >> 4;
        int n = 32 * wv + (lane & 31);
        int k = 16 * ks + (lane >> 5) * 8 + j;
        ws[idx] = (bf16)W3[k * 128 + n];
    } else if (idx < WTC2_OFF) {
        int t = idx - WTC1_OFF;
        int j = t & 7, lane = (t >> 3) & 63, f = t >> 9;
        int ks = f % 5; f /= 5;
        int nt = f & 1, g = f >> 1;
        int n = 16 * (2 * g + nt) + (lane & 15);
        int k = 32 * ks + (lane >> 4) * 8 + j;
        ws[idx] = (bf16)Wc1[k * 64 + n];
    } else {
        int t = idx - WTC2_OFF;
        int j = t & 7, lane = (t >> 3) & 63, f = t >> 9;
        int ks = f & 1, nt = f >> 1;
        int n = 16 * nt + (lane & 15);
        int k = 32 * ks + (lane >> 4) * 8 + j;
        ws[idx] = (bf16)Wc2[k * 32 + n];
    }
}

__device__ inline f32x16 z16() {
    f32x16 v;
#pragma unroll
    for (int i = 0; i < 16; ++i) v[i] = 0.0f;
    return v;
}
__device__ inline f32x4 z4() {
    f32x4 v;
#pragma unroll
    for (int i = 0; i < 4; ++i) v[i] = 0.0f;
    return v;
}

__global__ __launch_bounds__(256, 3) void fused_mlp(
    const float* __restrict__ x, const bf16* __restrict__ wt,
    const float* __restrict__ b1, const float* __restrict__ b2, const float* __restrict__ b3,
    const float* __restrict__ Ws, const float* __restrict__ bs,
    const float* __restrict__ bc1, const float* __restrict__ bc2,
    const float* __restrict__ Wc3, const float* __restrict__ bc3,
    float* __restrict__ out)
{
    // 52.7 KB total -> 3 blocks/CU (12 waves/CU)
    __shared__ __align__(16) bf16 sXb[32 * SX];    // x tile; later H2 (stride SH); later C2 region unused
    __shared__ __align__(16) bf16 sH1[32 * SH];    // H1 half (ping-pong); later C1 (stride SC1) + C2 (f32)
    __shared__ __align__(16) bf16 sCB[32 * SCB];   // combined [seq(128) | stat(32)]

    const int tid  = threadIdx.x;
    const int lane = tid & 63;
    const int wv   = tid >> 6;          // 0..3
    const int row0 = blockIdx.x * 32;

    // ---------- Phase A: x tile load + moments + stat features (no extra barrier) ----------
    {
        const int r = tid >> 3;       // row 0..31
        const int j = tid & 7;        // 8 threads per row
        const float* xr = x + (size_t)(row0 + r) * T_DIM;
        bf16* xb = sXb + r * SX;
        float s1 = 0.f, s2 = 0.f, s3 = 0.f, s4 = 0.f;
        float mn = 3.4e38f, mx = -3.4e38f;
#pragma unroll
        for (int i = 0; i < 12; ++i) {
            int c = j + 8 * i;        // float4 chunk 0..91
            if (c < 91) {
                float v0 = xr[4*c+0], v1 = xr[4*c+1], v2 = xr[4*c+2], v3 = xr[4*c+3];
                s1 += v0 + v1 + v2 + v3;
                float q0 = v0*v0, q1 = v1*v1, q2 = v2*v2, q3 = v3*v3;
                s2 += q0 + q1 + q2 + q3;
                s3 += q0*v0 + q1*v1 + q2*v2 + q3*v3;
                s4 += q0*q0 + q1*q1 + q2*q2 + q3*q3;
                mn = fminf(mn, fminf(fminf(v0, v1), fminf(v2, v3)));
                mx = fmaxf(mx, fmaxf(fmaxf(v0, v1), fmaxf(v2, v3)));
                bf16x4 p = { (bf16)v0, (bf16)v1, (bf16)v2, (bf16)v3 };
                *(bf16x4*)(xb + 4 * c) = p;
            } else if (c == 91) {
                float v0 = xr[364];
                float q0 = v0 * v0;
                s1 += v0; s2 += q0; s3 += q0 * v0; s4 += q0 * q0;
                mn = fminf(mn, v0); mx = fmaxf(mx, v0);
                bf16x4 p = { (bf16)v0, (bf16)0.0f, (bf16)0.0f, (bf16)0.0f };
                *(bf16x4*)(xb + 364) = p;
            }
        }
#pragma unroll
        for (int m = 1; m < 8; m <<= 1) {
            s1 += __shfl_xor(s1, m); s2 += __shfl_xor(s2, m);
            s3 += __shfl_xor(s3, m); s4 += __shfl_xor(s4, m);
            mn = fminf(mn, __shfl_xor(mn, m));
            mx = fmaxf(mx, __shfl_xor(mx, m));
        }
        // every j-thread now has the row moments: compute 4 stat-feature cols each
        const float Tf = (float)T_DIM;
        float mu = s1 / Tf;
        float M2 = fmaxf(s2 - s1 * mu, 0.0f);
        float M3 = s3 - 3.f * mu * s2 + 2.f * Tf * mu * mu * mu;
        float M4 = s4 - 4.f * mu * s3 + 6.f * mu * mu * s2 - 3.f * Tf * mu * mu * mu * mu;
        float var = M2 / (Tf - 1.f);
        float sd  = sqrtf(var);
        float sk  = (M3 / Tf) / (sd * sd * sd + 1e-8f);
        float ku  = (M4 / Tf) / (var * var + 1e-8f);
#pragma unroll
        for (int cc = 0; cc < 4; ++cc) {
            int n = 4 * j + cc;
            float v = bs[n]
                    + mu * Ws[0*32+n] + sd * Ws[1*32+n] + mn * Ws[2*32+n]
                    + mx * Ws[3*32+n] + sk * Ws[4*32+n] + ku * Ws[5*32+n];
            sCB[r * SCB + 128 + n] = (bf16)v;
        }
    }
    __syncthreads();

    const int l31   = lane & 31;
    const int lhalf = lane >> 5;

    // ---------- Layers 1+2 ping-pong over column/k halves ----------
    f32x16 accL2_0 = z16(), accL2_1 = z16();
#pragma unroll 1
    for (int p = 0; p < 2; ++p) {
        // L1 pass p: [32,368] x [368,256] -> H1 half (cols 256p..256p+255)
        {
            f32x16 acc0 = z16(), acc1 = z16();
            const bf16* ap = sXb + l31 * SX + lhalf * 8;
            const bf16* bp = wt + WT1_OFF + (size_t)((p * 4 + wv) * 2 * 23) * 512 + (size_t)lane * 8;
#pragma unroll 2
            for (int ks = 0; ks < 23; ++ks) {
                bf16x8 a  = *(const bf16x8*)(ap + 16 * ks);
                bf16x8 b0 = *(const bf16x8*)(bp + ks * 512);
                bf16x8 b1 = *(const bf16x8*)(bp + 11776 + ks * 512);
                acc0 = __builtin_amdgcn_mfma_f32_32x32x16_bf16(a, b0, acc0, 0, 0, 0);
                acc1 = __builtin_amdgcn_mfma_f32_32x32x16_bf16(a, b1, acc1, 0, 0, 0);
            }
#pragma unroll
            for (int nt = 0; nt < 2; ++nt) {
                const f32x16& A = nt ? acc1 : acc0;
                int colh = 64 * wv + 32 * nt + l31;        // 0..255 within half
                float bias = b1[256 * p + colh];
#pragma unroll
                for (int g = 0; g < 4; ++g) {
#pragma unroll
                    for (int rr = 0; rr < 4; ++rr) {
                        int rowi = rr + 8 * g + 4 * lhalf;
                        float v = fmaxf(A[4 * g + rr] + bias, 0.0f);
                        sH1[rowi * SH + colh] = (bf16)v;
                    }
                }
            }
        }
        __syncthreads();
        // L2 partial kh=p: accumulate [32,256]x[256,256] into accL2
        {
            const bf16* ap = sH1 + l31 * SH + lhalf * 8;
            const bf16* bp = wt + WT2_OFF + (size_t)((p * 4 + wv) * 2 * 16) * 512 + (size_t)lane * 8;
#pragma unroll 2
            for (int ks = 0; ks < 16; ++ks) {
                bf16x8 a  = *(const bf16x8*)(ap + 16 * ks);
                bf16x8 b0 = *(const bf16x8*)(bp + ks * 512);
                bf16x8 b1 = *(const bf16x8*)(bp + 8192 + ks * 512);
                accL2_0 = __builtin_amdgcn_mfma_f32_32x32x16_bf16(a, b0, accL2_0, 0, 0, 0);
                accL2_1 = __builtin_amdgcn_mfma_f32_32x32x16_bf16(a, b1, accL2_1, 0, 0, 0);
            }
        }
        if (p == 0) __syncthreads();   // protect sH1 before pass-1 overwrites it
    }
    // H2 epilogue into sXb region (stride SH); sXb (x) is dead now
    {
        bf16* H2 = sXb;
#pragma unroll
        for (int nt = 0; nt < 2; ++nt) {
            const f32x16& A = nt ? accL2_1 : accL2_0;
            int col = 64 * wv + 32 * nt + l31;
            float bias = b2[col];
#pragma unroll
            for (int g = 0; g < 4; ++g) {
#pragma unroll
                for (int rr = 0; rr < 4; ++rr) {
                    int rowi = rr + 8 * g + 4 * lhalf;
                    float v = fmaxf(A[4 * g + rr] + bias, 0.0f);
                    H2[rowi * SH + col] = (bf16)v;
                }
            }
        }
    }
    __syncthreads();

    // ---------- Layer 3: [32,256] x [256,128] -> seq (sCB cols 0..127) ----------
    {
        f32x16 acc = z16();
        const bf16* ap = sXb + l31 * SH + lhalf * 8;
        const bf16* bp = wt + WT3_OFF + (size_t)(wv * 16) * 512 + (size_t)lane * 8;
#pragma unroll 4
        for (int ks = 0; ks < 16; ++ks) {
            bf16x8 a = *(const bf16x8*)(ap + 16 * ks);
            bf16x8 b = *(const bf16x8*)(bp + ks * 512);
            acc = __builtin_amdgcn_mfma_f32_32x32x16_bf16(a, b, acc, 0, 0, 0);
        }
        int col = 32 * wv + l31;
        float bias = b3[col];
#pragma unroll
        for (int g = 0; g < 4; ++g) {
#pragma unroll
            for (int rr = 0; rr < 4; ++rr) {
                int rowi = rr + 8 * g + 4 * lhalf;
                float v = fmaxf(acc[4 * g + rr] + bias, 0.0f);
                sCB[rowi * SCB + col] = (bf16)v;
            }
        }
    }
    __syncthreads();

    // ---------- Layer c1: [32,160] x [160,64] -> C1 (16x16x32), C1 aliases sH1 ----------
    const int l15 = lane & 15;
    const int lq  = lane >> 4;
    const int gc1 = wv >> 1;
    {
        const int mt = wv & 1;
        f32x4 acc0 = z4(), acc1 = z4();
        const bf16* ap = sCB + (16 * mt + l15) * SCB + lq * 8;
        const bf16* bp = wt + WTC1_OFF + (size_t)gc1 * (2 * 5 * 512) + (size_t)lane * 8;
#pragma unroll
        for (int ks = 0; ks < 5; ++ks) {
            bf16x8 a  = *(const bf16x8*)(ap + 32 * ks);
            bf16x8 c0 = *(const bf16x8*)(bp + ks * 512);
            bf16x8 c1 = *(const bf16x8*)(bp + 2560 + ks * 512);
            acc0 = __builtin_amdgcn_mfma_f32_16x16x32_bf16(a, c0, acc0, 0, 0, 0);
            acc1 = __builtin_amdgcn_mfma_f32_16x16x32_bf16(a, c1, acc1, 0, 0, 0);
        }
        bf16* C1 = sH1;
#pragma unroll
        for (int nt = 0; nt < 2; ++nt) {
            const f32x4& A = nt ? acc1 : acc0;
            int col = 16 * (2 * gc1 + nt) + l15;
            float bias = bc1[col];
#pragma unroll
            for (int reg = 0; reg < 4; ++reg) {
                int m = 16 * mt + lq * 4 + reg;
                float v = fmaxf(A[reg] + bias, 0.0f);
                C1[m * SC1 + col] = (bf16)v;
            }
        }
    }
    __syncthreads();

    // ---------- Layer c2: [32,64] x [64,32] -> C2 (f32, aliases sH1 tail) ----------
    float* C2 = (float*)((char*)sH1 + 4608);
    {
        const int mt = wv & 1;
        f32x4 acc = z4();
        const bf16* ap = sH1 + (16 * mt + l15) * SC1 + lq * 8;
        const bf16* bp = wt + WTC2_OFF + (size_t)gc1 * (2 * 512) + (size_t)lane * 8;
#pragma unroll
        for (int ks = 0; ks < 2; ++ks) {
            bf16x8 a = *(const bf16x8*)(ap + 32 * ks);
            bf16x8 b = *(const bf16x8*)(bp + ks * 512);
            acc = __builtin_amdgcn_mfma_f32_16x16x32_bf16(a, b, acc, 0, 0, 0);
        }
        int col = 16 * gc1 + l15;
        float bias = bc2[col];
#pragma unroll
        for (int reg = 0; reg < 4; ++reg) {
            int m = 16 * mt + lq * 4 + reg;
            float v = fmaxf(acc[reg] + bias, 0.0f);
            C2[m * SC2 + col] = v;
        }
    }
    __syncthreads();

    // ---------- final: 32 -> 1 dot, sigmoid*4+6 ----------
    if (tid < 32) {
        const float* c2r = C2 + tid * SC2;
        float z = bc3[0];
#pragma unroll
        for (int k = 0; k < 32; ++k) z += c2r[k] * Wc3[k];
        float sg = 1.0f / (1.0f + __expf(-z));
        out[row0 + tid] = sg * 4.0f + 6.0f;
    }
}

extern "C" void kernel_launch(void* const* d_in, const int* in_sizes, int n_in,
                              void* d_out, int out_size, void* d_ws, size_t ws_size,
                              hipStream_t stream) {
    const float* x   = (const float*)d_in[0];
    const float* W1  = (const float*)d_in[1];
    const float* b1  = (const float*)d_in[2];
    const float* W2  = (const float*)d_in[3];
    const float* b2  = (const float*)d_in[4];
    const float* W3  = (const float*)d_in[5];
    const float* b3  = (const float*)d_in[6];
    const float* Ws  = (const float*)d_in[7];
    const float* bs  = (const float*)d_in[8];
    const float* Wc1 = (const float*)d_in[9];
    const float* bc1 = (const float*)d_in[10];
    const float* Wc2 = (const float*)d_in[11];
    const float* bc2 = (const float*)d_in[12];
    const float* Wc3 = (const float*)d_in[13];
    const float* bc3 = (const float*)d_in[14];
    float* out = (float*)d_out;
    bf16* wt = (bf16*)d_ws;

    const int B = in_sizes[0] / T_DIM;          // 65536
    prep_weights<<<(WTOTAL + 255) / 256, 256, 0, stream>>>(W1, W2, W3, Wc1, Wc2, wt);
    fused_mlp<<<B / 32, 256, 0, stream>>>(x, wt, b1, b2, b3, Ws, bs, bc1, bc2, Wc3, bc3, out);
}